// Round 6
// baseline (2096.820 us; speedup 1.0000x reference)
//
#include <hip/hip_runtime.h>
#include <hip/hip_bf16.h>

#define D     1024
#define PED   64
#define NHEAD 16
#define NB    2
#define NN    2048
#define NHB   32      // NB*NHEAD
#define DH    68      // (D+PED)/NHEAD
#define TT    4096    // NB*NN
#define CAP   68      // kept-entry capacity per row (64 + tie slack)

// ---------------- LayerNorm ----------------
__global__ __launch_bounds__(256) void ln_kernel(const float* __restrict__ sink,
                                                 const float* __restrict__ gw,
                                                 const float* __restrict__ bw,
                                                 float* __restrict__ feat)
{
    int row = blockIdx.x, t = threadIdx.x;
    const float* x = sink + (size_t)row * (D + PED);
    float4 v = *(const float4*)(x + (t << 2));
    float s = v.x + v.y + v.z + v.w;
    __shared__ float red[4];
    __shared__ float mu_s, rstd_s;
    for (int o = 32; o > 0; o >>= 1) s += __shfl_down(s, o);
    if ((t & 63) == 0) red[t >> 6] = s;
    __syncthreads();
    if (t == 0) mu_s = (red[0] + red[1] + red[2] + red[3]) * (1.0f / D);
    __syncthreads();
    float mu = mu_s;
    float dx = v.x - mu, dy = v.y - mu, dz = v.z - mu, dw = v.w - mu;
    float s2 = dx*dx + dy*dy + dz*dz + dw*dw;
    for (int o = 32; o > 0; o >>= 1) s2 += __shfl_down(s2, o);
    if ((t & 63) == 0) red[t >> 6] = s2;
    __syncthreads();
    if (t == 0) rstd_s = rsqrtf((red[0] + red[1] + red[2] + red[3]) * (1.0f / D) + 1e-6f);
    __syncthreads();
    float rstd = rstd_s;
    float4 gv = *(const float4*)(gw + (t << 2));
    float4 bv = *(const float4*)(bw + (t << 2));
    float4 o4;
    o4.x = dx * rstd * gv.x + bv.x;
    o4.y = dy * rstd * gv.y + bv.y;
    o4.z = dz * rstd * gv.z + bv.z;
    o4.w = dw * rstd * gv.w + bv.w;
    *(float4*)(feat + (size_t)row * D + (t << 2)) = o4;
}

// ---------------- fp32 SGEMM with bias: 128x64 tile, 8x4 acc ----------------
__global__ __launch_bounds__(256) void sgemm_bias(const float* __restrict__ A, int lda,
                                                  const float* __restrict__ W, int ldw,
                                                  const float* __restrict__ bias,
                                                  float* __restrict__ C, int ldc)
{
    const int K = 1024;
    __shared__ float At[8][128];
    __shared__ float Bt[8][64];
    int t = threadIdx.x;
    int m0 = blockIdx.y << 7, n0 = blockIdx.x << 6;
    int tx = t & 15, ty = t >> 4;        // 16 col-groups x 16 row-groups
    float acc[8][4] = {};
    int ar = t >> 1, ak0 = (t & 1) << 2; // A loader: row 0..127, k-offset 0/4
    int bc = t & 63, bk = t >> 6;        // B loader
    const float* Aptr = A + (size_t)(m0 + ar) * lda + ak0;
    const float* Wptr = W + (size_t)bk * ldw + n0 + bc;
    for (int kt = 0; kt < K; kt += 8) {
        float4 av = *(const float4*)Aptr;
        At[ak0 + 0][ar] = av.x;
        At[ak0 + 1][ar] = av.y;
        At[ak0 + 2][ar] = av.z;
        At[ak0 + 3][ar] = av.w;
        Bt[bk][bc]      = Wptr[0];
        Bt[bk + 4][bc]  = Wptr[(size_t)4 * ldw];
        __syncthreads();
        #pragma unroll
        for (int k = 0; k < 8; k++) {
            float4 a0 = *(const float4*)&At[k][ty << 3];
            float4 a1 = *(const float4*)&At[k][(ty << 3) + 4];
            float4 b4 = *(const float4*)&Bt[k][tx << 2];
            float ar_[8] = {a0.x, a0.y, a0.z, a0.w, a1.x, a1.y, a1.z, a1.w};
            float br_[4] = {b4.x, b4.y, b4.z, b4.w};
            #pragma unroll
            for (int r = 0; r < 8; r++)
                #pragma unroll
                for (int c = 0; c < 4; c++)
                    acc[r][c] = fmaf(ar_[r], br_[c], acc[r][c]);
        }
        __syncthreads();
        Aptr += 8;
        Wptr += (size_t)8 * ldw;
    }
    const float* bp = bias + n0 + (tx << 2);
    float4 bb4 = {bp[0], bp[1], bp[2], bp[3]};
    #pragma unroll
    for (int r = 0; r < 8; r++) {
        float* Crow = C + (size_t)(m0 + (ty << 3) + r) * ldc + n0 + (tx << 2);
        float4 o;
        o.x = acc[r][0] + bb4.x;
        o.y = acc[r][1] + bb4.y;
        o.z = acc[r][2] + bb4.z;
        o.w = acc[r][3] + bb4.w;
        *(float4*)Crow = o;
    }
}

// ---------------- repack into per-head q/k/v (scale folded into q; exact: 0.125 = 2^-3) ----------------
__global__ __launch_bounds__(256) void repack_kernel(const float* __restrict__ q,
                                                     const float* __restrict__ kv,
                                                     const float* __restrict__ sink,
                                                     float* __restrict__ qh,
                                                     float* __restrict__ kh,
                                                     float* __restrict__ vh)
{
    unsigned gid = blockIdx.x * 256u + threadIdx.x;
    if (gid >= (unsigned)NHB * NN * DH) return;
    int d = gid % DH;
    unsigned r2 = gid / DH;
    int i = r2 & (NN - 1);
    int hb = r2 >> 11;
    int hh = hb & (NHEAD - 1), b0 = hb >> 4;
    int row = (b0 << 11) + i;
    int c = hh * DH + d;
    float qv, kvv, vv;
    if (c < D) {
        qv  = q [(size_t)row * D + c];
        kvv = kv[(size_t)row * (2 * D) + c];
        vv  = kv[(size_t)row * (2 * D) + D + c];
    } else {
        float pe = sink[(size_t)row * (D + PED) + c];  // concat dim c>=D maps to sink col c
        qv = pe; kvv = pe; vv = pe;
    }
    qh[gid] = 0.125f * qv;
    kh[gid] = kvv;
    vh[gid] = vv;
}

// ---------------- sim = Qh · Khᵀ per head (64x64 tiles) ----------------
__global__ __launch_bounds__(256) void sim_kernel(const float* __restrict__ qh,
                                                  const float* __restrict__ kh,
                                                  float* __restrict__ simBuf, int hb0)
{
    __shared__ float Qt[DH * DH]; // [d][r] transposed, stride 68, r<64
    __shared__ float Kt[DH * DH];
    int g = blockIdx.z, hb = hb0 + g;
    int i0 = blockIdx.y << 6, j0 = blockIdx.x << 6;
    int t = threadIdx.x;
    const float* qbase = qh + ((size_t)hb * NN + i0) * DH;
    const float* kbase = kh + ((size_t)hb * NN + j0) * DH;
    for (int e = t; e < 64 * DH; e += 256) {
        int r = e / DH, d = e - r * DH;
        Qt[d * DH + r] = qbase[e];
        Kt[d * DH + r] = kbase[e];
    }
    __syncthreads();
    int tx = t & 15, ty = t >> 4;
    float acc[4][4] = {};
    #pragma unroll 4
    for (int k = 0; k < DH; k++) {
        float4 a4 = *(const float4*)&Qt[k * DH + (ty << 2)];
        float4 b4 = *(const float4*)&Kt[k * DH + (tx << 2)];
        float ar_[4] = {a4.x, a4.y, a4.z, a4.w};
        float br_[4] = {b4.x, b4.y, b4.z, b4.w};
        #pragma unroll
        for (int r = 0; r < 4; r++)
            #pragma unroll
            for (int c = 0; c < 4; c++)
                acc[r][c] = fmaf(ar_[r], br_[c], acc[r][c]);
    }
    #pragma unroll
    for (int r = 0; r < 4; r++) {
        float4 o;
        o.x = acc[r][0]; o.y = acc[r][1]; o.z = acc[r][2]; o.w = acc[r][3];
        *(float4*)(simBuf + ((size_t)g * NN + i0 + (ty << 2) + r) * NN + j0 + (tx << 2)) = o;
    }
}

// ---------------- exact top-k threshold (radix select, wave-optimized) ----------------
__device__ __forceinline__ unsigned fmap(float f) {
    unsigned u = __float_as_uint(f);
    return (u & 0x80000000u) ? ~u : (u | 0x80000000u);
}
__device__ __forceinline__ float funmap(unsigned u) {
    return __uint_as_float((u & 0x80000000u) ? (u & 0x7fffffffu) : ~u);
}

__global__ __launch_bounds__(256) void topk_kernel(const float* __restrict__ sim, int hb0,
                                                   const int* __restrict__ topt,
                                                   int* __restrict__ keptIdx,
                                                   float* __restrict__ keptVal,
                                                   int* __restrict__ keptCnt)
{
    int bid = blockIdx.x;              // g*2048 + i
    int g = bid >> 11, i = bid & (NN - 1);
    int hb = hb0 + g;
    const float* row = sim + ((size_t)bid << 11);
    __shared__ int hist[4][256];       // per-wave replicated histograms
    __shared__ int wsum[4];
    __shared__ unsigned sh_prefix;
    __shared__ int sh_k, sh_cnt;
    int t = threadIdx.x;
    int wave = t >> 6, lane = t & 63;
    unsigned lk[8];
    #pragma unroll
    for (int c = 0; c < 8; c++) lk[c] = fmap(row[t + (c << 8)]);
    if (t == 0) { sh_k = topt[0]; sh_prefix = 0u; sh_cnt = 0; }
    __syncthreads();
    for (int pass = 0; pass < 4; pass++) {
        int shift = 24 - (pass << 3);
        // zero own histogram copy (wave-local; prior-pass readers done at last barrier)
        #pragma unroll
        for (int j = 0; j < 4; j++) hist[wave][lane + (j << 6)] = 0;
        unsigned prefix = sh_prefix;
        int k = sh_k;
        if (pass == 0) {
            // exponent-clustered buckets: wave-uniform ballot counting, no atomics
            #pragma unroll
            for (int c = 0; c < 8; c++) {
                unsigned b = lk[c] >> 24;
                bool pending = true;
                while (true) {
                    unsigned long long act = __ballot(pending);
                    if (!act) break;
                    int src = __ffsll((unsigned long long)act) - 1;
                    unsigned bb = (unsigned)__shfl((int)b, src);
                    unsigned long long match = __ballot(pending && (b == bb));
                    if (lane == src) hist[wave][bb] += (int)__popcll(match);
                    if (b == bb) pending = false;
                }
            }
        } else {
            unsigned hm = 0xFFFFFFFFu << (shift + 8);
            #pragma unroll
            for (int c = 0; c < 8; c++) {
                unsigned u = lk[c];
                if ((u & hm) == prefix) atomicAdd(&hist[wave][(u >> shift) & 255], 1);
            }
        }
        __syncthreads();
        // merge 4 copies for bin t
        int tot = hist[0][t] + hist[1][t] + hist[2][t] + hist[3][t];
        // within-wave inclusive suffix sum over lanes (bin index ascending with lane)
        int v = tot;
        #pragma unroll
        for (int off = 1; off < 64; off <<= 1) {
            int u = __shfl_down(v, off);
            if (lane + off < 64) v += u;
        }
        if (lane == 0) wsum[wave] = v;
        __syncthreads();
        int addHigher = 0;
        #pragma unroll
        for (int w = 0; w < 4; w++) if (w > wave) addHigher += wsum[w];
        int above = addHigher + (v - tot);   // count of elements in bins > t
        if (above < k && k <= above + tot) {
            sh_prefix = prefix | ((unsigned)t << shift);
            sh_k = k - above;
        }
        __syncthreads();
    }
    unsigned kthKey = sh_prefix;
    size_t base = ((size_t)hb * NN + i) * CAP;
    #pragma unroll
    for (int c = 0; c < 8; c++) {
        unsigned u = lk[c];
        if (u >= kthKey) {
            int p = atomicAdd(&sh_cnt, 1);
            if (p < CAP) {
                keptIdx[base + p] = t + (c << 8);
                keptVal[base + p] = funmap(u);
            }
        }
    }
    __syncthreads();
    if (t == 0) keptCnt[hb * NN + i] = (sh_cnt < CAP) ? sh_cnt : CAP;
}

// ---------------- column partition function Z_j (atomic scatter over kept entries) ----------------
__global__ __launch_bounds__(256) void colz_kernel(const int* __restrict__ keptIdx,
                                                   const float* __restrict__ keptVal,
                                                   const int* __restrict__ keptCnt,
                                                   float* __restrict__ colZ)
{
    unsigned gid = blockIdx.x * 256u + threadIdx.x;
    if (gid >= (unsigned)NHB * NN * CAP) return;
    int p = gid % CAP;
    unsigned rid = gid / CAP; // hb*2048 + i
    if (p < keptCnt[rid]) {
        int hb = rid >> 11;
        atomicAdd(&colZ[(hb << 11) + keptIdx[(size_t)rid * CAP + p]],
                  expf(keptVal[(size_t)rid * CAP + p]));
    }
}

// ---------------- per-head stats: empty-column count, ΣV over empty cols, ΣV over all cols ----------------
__global__ void stats_kernel(const float* __restrict__ colZ, const float* __restrict__ vh,
                             int* __restrict__ nE, float* __restrict__ vsumE,
                             float* __restrict__ vsumAll)
{
    int hb = blockIdx.x;
    int t = threadIdx.x;   // blockDim = 272 = 4*68
    int ty = t / DH, d = t - ty * DH;
    float aAll = 0.f, aE = 0.f;
    int cE = 0;
    for (int j = ty; j < NN; j += 4) {
        float z = colZ[(hb << 11) + j];
        float vv = vh[((size_t)(hb << 11) + j) * DH + d];
        aAll += vv;
        if (z == 0.0f) { aE += vv; cE++; }
    }
    __shared__ float sAll[4][DH], sE[4][DH];
    __shared__ int sC[4];
    sAll[ty][d] = aAll;
    sE[ty][d] = aE;
    if (d == 0) sC[ty] = cE;
    __syncthreads();
    if (ty == 0) {
        vsumAll[hb * DH + d] = sAll[0][d] + sAll[1][d] + sAll[2][d] + sAll[3][d];
        vsumE[hb * DH + d]   = sE[0][d] + sE[1][d] + sE[2][d] + sE[3][d];
        if (d == 0) nE[hb] = sC[0] + sC[1] + sC[2] + sC[3];
    }
}

// ---------------- sparse PV + renormalization; writes outcat (cols<1024) and d_out PE cols directly ----------------
__global__ __launch_bounds__(128) void pv_kernel(const int* __restrict__ keptIdx,
                                                 const float* __restrict__ keptVal,
                                                 const int* __restrict__ keptCnt,
                                                 const float* __restrict__ colZ,
                                                 const float* __restrict__ vh,
                                                 const int* __restrict__ nE,
                                                 const float* __restrict__ vsumE,
                                                 const float* __restrict__ vsumAll,
                                                 float* __restrict__ outcat,
                                                 float* __restrict__ dout)
{
    int bid = blockIdx.x;           // hb*2048 + i
    int hb = bid >> 11, i = bid & (NN - 1);
    int t = threadIdx.x;
    __shared__ float w[CAP];
    __shared__ int jj[CAP];
    __shared__ float rowsum_s;
    int cnt = keptCnt[bid];
    size_t base = (size_t)bid * CAP;
    if (t < cnt) {
        int j = keptIdx[base + t];
        jj[t] = j;
        w[t] = expf(keptVal[base + t]) / colZ[(hb << 11) + j];
    }
    __syncthreads();
    if (t == 0) {
        float s = 0.f;
        for (int p = 0; p < cnt; p++) s += w[p];
        rowsum_s = s + (float)nE[hb] * (1.0f / NN) + (float)NN * 1e-6f;
    }
    __syncthreads();
    if (t < DH) {
        float acc = 1e-6f * vsumAll[hb * DH + t] + (1.0f / NN) * vsumE[hb * DH + t];
        const float* vbase = vh + ((size_t)(hb << 11)) * DH;
        for (int p = 0; p < cnt; p++)
            acc = fmaf(w[p], vbase[(size_t)jj[p] * DH + t], acc);
        float val = acc / rowsum_s;
        int hh = hb & (NHEAD - 1), b0 = hb >> 4;
        int row = (b0 << 11) + i;
        int c = hh * DH + t;
        if (c < D) outcat[(size_t)row * D + c] = val;
        else       dout[(size_t)row * (D + PED) + c] = val;
    }
}

// ---------------- launch ----------------
extern "C" void kernel_launch(void* const* d_in, const int* in_sizes, int n_in,
                              void* d_out, int out_size, void* d_ws, size_t ws_size,
                              hipStream_t stream)
{
    (void)in_sizes; (void)n_in; (void)out_size;
    const float* sink = (const float*)d_in[0];
    const float* gno  = (const float*)d_in[1];
    const float* bno  = (const float*)d_in[2];
    const float* Wq   = (const float*)d_in[3];
    const float* bq   = (const float*)d_in[4];
    const float* Wkv  = (const float*)d_in[5];
    const float* bkv  = (const float*)d_in[6];
    const float* Wout = (const float*)d_in[7];
    const float* bout = (const float*)d_in[8];
    const int*   topt = (const int*)d_in[9];
    float* out = (float*)d_out;

    char* ws = (char*)d_ws;
    // Region A (64 MB): feat(16) + q(16) + kv(32). Dead after repack_kernel;
    // reused as simBuf (4 heads x 16 MB) for the sim/topk sweep.
    float* feat = (float*)(ws + 0);
    float* q    = (float*)(ws + (size_t)TT * D * 4);
    float* kv   = (float*)(ws + (size_t)2 * TT * D * 4);
    size_t off  = (size_t)4 * TT * D * 4;                                    // 64 MB
    float* qh      = (float*)(ws + off); off += (size_t)NHB * NN * DH * 4;   // 17.8 MB
    float* kh      = (float*)(ws + off); off += (size_t)NHB * NN * DH * 4;
    float* vh      = (float*)(ws + off); off += (size_t)NHB * NN * DH * 4;
    int*   keptIdx = (int*)  (ws + off); off += (size_t)NHB * NN * CAP * 4;
    float* keptVal = (float*)(ws + off); off += (size_t)NHB * NN * CAP * 4;
    int*   keptCnt = (int*)  (ws + off); off += (size_t)NHB * NN * 4;
    float* colZ    = (float*)(ws + off); off += (size_t)NHB * NN * 4;
    int*   nE      = (int*)  (ws + off); off += 256;
    float* vsumE   = (float*)(ws + off); off += (size_t)NHB * DH * 4 + 192;  // pad to 256
    float* vsumAll = (float*)(ws + off); off += (size_t)NHB * DH * 4 + 192;
    float* outcat  = (float*)(ws + off); off += (size_t)TT * D * 4;          // 16 MB

    // simBuf: prefer tail of ws if it holds >4 heads, else alias region A (4 heads).
    size_t simBytesPerHead = (size_t)NN * NN * 4;                            // 16 MB
    size_t tail = (ws_size > off) ? (ws_size - off) : 0;
    int Gtail = (int)(tail / simBytesPerHead);
    float* simBuf;
    int G;
    if (Gtail > 4) {
        simBuf = (float*)(ws + off);
        G = (Gtail < NHB) ? Gtail : NHB;
    } else {
        simBuf = (float*)ws;   // region A, free after repack
        G = 4;
    }

    ln_kernel<<<TT, 256, 0, stream>>>(sink, gno, bno, feat);
    sgemm_bias<<<dim3(D / 64, TT / 128), 256, 0, stream>>>(feat, D, Wq, D, bq, q, D);
    sgemm_bias<<<dim3(2 * D / 64, TT / 128), 256, 0, stream>>>(feat, D, Wkv, 2 * D, bkv, kv, 2 * D);
    repack_kernel<<<((unsigned)NHB * NN * DH + 255) / 256, 256, 0, stream>>>(q, kv, sink, qh, kh, vh);
    hipMemsetAsync(colZ, 0, (size_t)NHB * NN * 4, stream);

    for (int hb0 = 0; hb0 < NHB; hb0 += G) {
        int gc = (NHB - hb0 < G) ? (NHB - hb0) : G;
        sim_kernel<<<dim3(NN / 64, NN / 64, gc), 256, 0, stream>>>(qh, kh, simBuf, hb0);
        topk_kernel<<<gc * NN, 256, 0, stream>>>(simBuf, hb0, topt, keptIdx, keptVal, keptCnt);
    }

    colz_kernel<<<((unsigned)NHB * NN * CAP + 255) / 256, 256, 0, stream>>>(keptIdx, keptVal, keptCnt, colZ);
    stats_kernel<<<NHB, 4 * DH, 0, stream>>>(colZ, vh, nE, vsumE, vsumAll);
    pv_kernel<<<NHB * NN, 128, 0, stream>>>(keptIdx, keptVal, keptCnt, colZ, vh, nE, vsumE, vsumAll, outcat, out);
    sgemm_bias<<<dim3(D / 64, TT / 128), 256, 0, stream>>>(outcat, D, Wout, D, bout, out, D + PED);
}

// Round 7
// 1746.814 us; speedup vs baseline: 1.2004x; 1.2004x over previous
//
#include <hip/hip_runtime.h>
#include <hip/hip_bf16.h>

#define D     1024
#define PED   64
#define NHEAD 16
#define NB    2
#define NN    2048
#define NHB   32      // NB*NHEAD
#define DH    68      // (D+PED)/NHEAD
#define TT    4096    // NB*NN
#define CAP   68      // kept-entry capacity per row (64 + tie slack)

// ---------------- LayerNorm ----------------
__global__ __launch_bounds__(256) void ln_kernel(const float* __restrict__ sink,
                                                 const float* __restrict__ gw,
                                                 const float* __restrict__ bw,
                                                 float* __restrict__ feat)
{
    int row = blockIdx.x, t = threadIdx.x;
    const float* x = sink + (size_t)row * (D + PED);
    float4 v = *(const float4*)(x + (t << 2));
    float s = v.x + v.y + v.z + v.w;
    __shared__ float red[4];
    __shared__ float mu_s, rstd_s;
    for (int o = 32; o > 0; o >>= 1) s += __shfl_down(s, o);
    if ((t & 63) == 0) red[t >> 6] = s;
    __syncthreads();
    if (t == 0) mu_s = (red[0] + red[1] + red[2] + red[3]) * (1.0f / D);
    __syncthreads();
    float mu = mu_s;
    float dx = v.x - mu, dy = v.y - mu, dz = v.z - mu, dw = v.w - mu;
    float s2 = dx*dx + dy*dy + dz*dz + dw*dw;
    for (int o = 32; o > 0; o >>= 1) s2 += __shfl_down(s2, o);
    if ((t & 63) == 0) red[t >> 6] = s2;
    __syncthreads();
    if (t == 0) rstd_s = rsqrtf((red[0] + red[1] + red[2] + red[3]) * (1.0f / D) + 1e-6f);
    __syncthreads();
    float rstd = rstd_s;
    float4 gv = *(const float4*)(gw + (t << 2));
    float4 bv = *(const float4*)(bw + (t << 2));
    float4 o4;
    o4.x = dx * rstd * gv.x + bv.x;
    o4.y = dy * rstd * gv.y + bv.y;
    o4.z = dz * rstd * gv.z + bv.z;
    o4.w = dw * rstd * gv.w + bv.w;
    *(float4*)(feat + (size_t)row * D + (t << 2)) = o4;
}

// ---------------- fp32 SGEMM with bias (round-5 proven 64x64 tile) ----------------
__global__ __launch_bounds__(256) void sgemm_bias(const float* __restrict__ A, int lda,
                                                  const float* __restrict__ W, int ldw,
                                                  const float* __restrict__ bias,
                                                  float* __restrict__ C, int ldc)
{
    const int K = 1024;
    __shared__ float At[8][68];
    __shared__ float Bt[8][68];
    int t = threadIdx.x;
    int m0 = blockIdx.y << 6, n0 = blockIdx.x << 6;
    int tx = t & 15, ty = t >> 4;
    float acc[4][4] = {};
    int ar = t >> 3, ak = t & 7;   // A loader
    int bc = t & 63, bk = t >> 6;  // B loader
    const float* Aptr = A + (size_t)(m0 + ar) * lda + ak;
    const float* Wptr = W + (size_t)bk * ldw + n0 + bc;
    for (int kt = 0; kt < K; kt += 8) {
        At[ak][ar]      = Aptr[0];
        At[ak][ar + 32] = Aptr[(size_t)32 * lda];
        Bt[bk][bc]      = Wptr[0];
        Bt[bk + 4][bc]  = Wptr[(size_t)4 * ldw];
        __syncthreads();
        #pragma unroll
        for (int k = 0; k < 8; k++) {
            float4 a4 = *(const float4*)&At[k][ty << 2];
            float4 b4 = *(const float4*)&Bt[k][tx << 2];
            float ar_[4] = {a4.x, a4.y, a4.z, a4.w};
            float br_[4] = {b4.x, b4.y, b4.z, b4.w};
            #pragma unroll
            for (int r = 0; r < 4; r++)
                #pragma unroll
                for (int c = 0; c < 4; c++)
                    acc[r][c] = fmaf(ar_[r], br_[c], acc[r][c]);
        }
        __syncthreads();
        Aptr += 8;
        Wptr += (size_t)8 * ldw;
    }
    #pragma unroll
    for (int r = 0; r < 4; r++) {
        float* Crow = C + (size_t)(m0 + (ty << 2) + r) * ldc + n0 + (tx << 2);
        const float* bp = bias + n0 + (tx << 2);
        float4 o;
        o.x = acc[r][0] + bp[0];
        o.y = acc[r][1] + bp[1];
        o.z = acc[r][2] + bp[2];
        o.w = acc[r][3] + bp[3];
        *(float4*)Crow = o;
    }
}

// ---------------- repack into per-head q/k/v (scale folded into q; exact: 0.125 = 2^-3) ----------------
__global__ __launch_bounds__(256) void repack_kernel(const float* __restrict__ q,
                                                     const float* __restrict__ kv,
                                                     const float* __restrict__ sink,
                                                     float* __restrict__ qh,
                                                     float* __restrict__ kh,
                                                     float* __restrict__ vh)
{
    unsigned gid = blockIdx.x * 256u + threadIdx.x;
    if (gid >= (unsigned)NHB * NN * DH) return;
    int d = gid % DH;
    unsigned r2 = gid / DH;
    int i = r2 & (NN - 1);
    int hb = r2 >> 11;
    int hh = hb & (NHEAD - 1), b0 = hb >> 4;
    int row = (b0 << 11) + i;
    int c = hh * DH + d;
    float qv, kvv, vv;
    if (c < D) {
        qv  = q [(size_t)row * D + c];
        kvv = kv[(size_t)row * (2 * D) + c];
        vv  = kv[(size_t)row * (2 * D) + D + c];
    } else {
        float pe = sink[(size_t)row * (D + PED) + c];  // concat dim c>=D maps to sink col c
        qv = pe; kvv = pe; vv = pe;
    }
    qh[gid] = 0.125f * qv;
    kh[gid] = kvv;
    vh[gid] = vv;
}

// ---------------- sim = Qh · Khᵀ per head (64x64 tiles) ----------------
__global__ __launch_bounds__(256) void sim_kernel(const float* __restrict__ qh,
                                                  const float* __restrict__ kh,
                                                  float* __restrict__ simBuf, int hb0)
{
    __shared__ float Qt[DH * DH]; // [d][r] transposed, stride 68, r<64
    __shared__ float Kt[DH * DH];
    int g = blockIdx.z, hb = hb0 + g;
    int i0 = blockIdx.y << 6, j0 = blockIdx.x << 6;
    int t = threadIdx.x;
    const float* qbase = qh + ((size_t)hb * NN + i0) * DH;
    const float* kbase = kh + ((size_t)hb * NN + j0) * DH;
    for (int e = t; e < 64 * DH; e += 256) {
        int r = e / DH, d = e - r * DH;
        Qt[d * DH + r] = qbase[e];
        Kt[d * DH + r] = kbase[e];
    }
    __syncthreads();
    int tx = t & 15, ty = t >> 4;
    float acc[4][4] = {};
    #pragma unroll 4
    for (int k = 0; k < DH; k++) {
        float4 a4 = *(const float4*)&Qt[k * DH + (ty << 2)];
        float4 b4 = *(const float4*)&Kt[k * DH + (tx << 2)];
        float ar_[4] = {a4.x, a4.y, a4.z, a4.w};
        float br_[4] = {b4.x, b4.y, b4.z, b4.w};
        #pragma unroll
        for (int r = 0; r < 4; r++)
            #pragma unroll
            for (int c = 0; c < 4; c++)
                acc[r][c] = fmaf(ar_[r], br_[c], acc[r][c]);
    }
    #pragma unroll
    for (int r = 0; r < 4; r++) {
        float4 o;
        o.x = acc[r][0]; o.y = acc[r][1]; o.z = acc[r][2]; o.w = acc[r][3];
        *(float4*)(simBuf + ((size_t)g * NN + i0 + (ty << 2) + r) * NN + j0 + (tx << 2)) = o;
    }
}

// ---------------- exact top-k threshold: wave-per-row bisection (no LDS/barriers/atomics) ----------------
__device__ __forceinline__ unsigned fmap(float f) {
    unsigned u = __float_as_uint(f);
    return (u & 0x80000000u) ? ~u : (u | 0x80000000u);
}
__device__ __forceinline__ float funmap(unsigned u) {
    return __uint_as_float((u & 0x80000000u) ? (u & 0x7fffffffu) : ~u);
}

__device__ __forceinline__ int waveCountGE(const unsigned* u, unsigned piv) {
    int c = 0;
    #pragma unroll
    for (int j = 0; j < 32; j++) c += (u[j] >= piv) ? 1 : 0;
    #pragma unroll
    for (int o = 32; o > 0; o >>= 1) c += __shfl_down(c, o);
    return __shfl(c, 0);   // broadcast lane-0 total to all 64 lanes
}

__global__ __launch_bounds__(256) void topk_kernel(const float* __restrict__ sim, int hb0,
                                                   const int* __restrict__ topt,
                                                   int* __restrict__ keptIdx,
                                                   float* __restrict__ keptVal,
                                                   int* __restrict__ keptCnt)
{
    int rid = (blockIdx.x << 2) + (threadIdx.x >> 6);   // row within chunk: g*2048 + i
    int lane = threadIdx.x & 63;
    int g = rid >> 11, i = rid & (NN - 1);
    int hb = hb0 + g;
    const float* row = sim + ((size_t)rid << 11);
    int k = topt[0];

    unsigned u[32];
    #pragma unroll
    for (int c = 0; c < 32; c++) u[c] = fmap(row[(c << 6) + lane]);

    // bisection for exact k-th largest key: largest T with count(>=T) >= k
    unsigned lo = 0u, hi = 0xFFFFFFFFu;
    while (lo < hi) {
        unsigned mid = lo + ((hi - lo) >> 1) + 1u;
        int cnt = waveCountGE(u, mid);
        if (cnt >= k) lo = mid; else hi = mid - 1u;
    }
    unsigned kth = lo;
    int total = waveCountGE(u, kth);

    // extraction: ballot prefix positions, capped at CAP
    size_t base = ((size_t)hb * NN + i) * CAP;
    int pbase = 0;
    #pragma unroll
    for (int c = 0; c < 32; c++) {
        bool p = (u[c] >= kth);
        unsigned long long m = __ballot(p);
        if (p) {
            int pos = pbase + (int)__popcll(m & ((1ull << lane) - 1ull));
            if (pos < CAP) {
                keptIdx[base + pos] = (c << 6) + lane;
                keptVal[base + pos] = funmap(u[c]);
            }
        }
        pbase += (int)__popcll(m);
    }
    if (lane == 0) keptCnt[hb * NN + i] = (total < CAP) ? total : CAP;
}

// ---------------- column partition function Z_j (atomic scatter over kept entries) ----------------
__global__ __launch_bounds__(256) void colz_kernel(const int* __restrict__ keptIdx,
                                                   const float* __restrict__ keptVal,
                                                   const int* __restrict__ keptCnt,
                                                   float* __restrict__ colZ)
{
    unsigned gid = blockIdx.x * 256u + threadIdx.x;
    if (gid >= (unsigned)NHB * NN * CAP) return;
    int p = gid % CAP;
    unsigned rid = gid / CAP; // hb*2048 + i
    if (p < keptCnt[rid]) {
        int hb = rid >> 11;
        atomicAdd(&colZ[(hb << 11) + keptIdx[(size_t)rid * CAP + p]],
                  expf(keptVal[(size_t)rid * CAP + p]));
    }
}

// ---------------- per-head stats: empty-column count, ΣV over empty cols, ΣV over all cols ----------------
__global__ void stats_kernel(const float* __restrict__ colZ, const float* __restrict__ vh,
                             int* __restrict__ nE, float* __restrict__ vsumE,
                             float* __restrict__ vsumAll)
{
    int hb = blockIdx.x;
    int t = threadIdx.x;   // blockDim = 272 = 4*68
    int ty = t / DH, d = t - ty * DH;
    float aAll = 0.f, aE = 0.f;
    int cE = 0;
    for (int j = ty; j < NN; j += 4) {
        float z = colZ[(hb << 11) + j];
        float vv = vh[((size_t)(hb << 11) + j) * DH + d];
        aAll += vv;
        if (z == 0.0f) { aE += vv; cE++; }
    }
    __shared__ float sAll[4][DH], sE[4][DH];
    __shared__ int sC[4];
    sAll[ty][d] = aAll;
    sE[ty][d] = aE;
    if (d == 0) sC[ty] = cE;
    __syncthreads();
    if (ty == 0) {
        vsumAll[hb * DH + d] = sAll[0][d] + sAll[1][d] + sAll[2][d] + sAll[3][d];
        vsumE[hb * DH + d]   = sE[0][d] + sE[1][d] + sE[2][d] + sE[3][d];
        if (d == 0) nE[hb] = sC[0] + sC[1] + sC[2] + sC[3];
    }
}

// ---------------- sparse PV + renormalization; writes outcat (cols<1024) and d_out PE cols directly ----------------
__global__ __launch_bounds__(128) void pv_kernel(const int* __restrict__ keptIdx,
                                                 const float* __restrict__ keptVal,
                                                 const int* __restrict__ keptCnt,
                                                 const float* __restrict__ colZ,
                                                 const float* __restrict__ vh,
                                                 const int* __restrict__ nE,
                                                 const float* __restrict__ vsumE,
                                                 const float* __restrict__ vsumAll,
                                                 float* __restrict__ outcat,
                                                 float* __restrict__ dout)
{
    int bid = blockIdx.x;           // hb*2048 + i
    int hb = bid >> 11, i = bid & (NN - 1);
    int t = threadIdx.x;
    __shared__ float w[CAP];
    __shared__ int jj[CAP];
    __shared__ float rowsum_s;
    int cnt = keptCnt[bid];
    size_t base = (size_t)bid * CAP;
    if (t < cnt) {
        int j = keptIdx[base + t];
        jj[t] = j;
        w[t] = expf(keptVal[base + t]) / colZ[(hb << 11) + j];
    }
    __syncthreads();
    if (t == 0) {
        float s = 0.f;
        for (int p = 0; p < cnt; p++) s += w[p];
        rowsum_s = s + (float)nE[hb] * (1.0f / NN) + (float)NN * 1e-6f;
    }
    __syncthreads();
    if (t < DH) {
        float acc = 1e-6f * vsumAll[hb * DH + t] + (1.0f / NN) * vsumE[hb * DH + t];
        const float* vbase = vh + ((size_t)(hb << 11)) * DH;
        for (int p = 0; p < cnt; p++)
            acc = fmaf(w[p], vbase[(size_t)jj[p] * DH + t], acc);
        float val = acc / rowsum_s;
        int hh = hb & (NHEAD - 1), b0 = hb >> 4;
        int row = (b0 << 11) + i;
        int c = hh * DH + t;
        if (c < D) outcat[(size_t)row * D + c] = val;
        else       dout[(size_t)row * (D + PED) + c] = val;
    }
}

// ---------------- launch ----------------
extern "C" void kernel_launch(void* const* d_in, const int* in_sizes, int n_in,
                              void* d_out, int out_size, void* d_ws, size_t ws_size,
                              hipStream_t stream)
{
    (void)in_sizes; (void)n_in; (void)out_size;
    const float* sink = (const float*)d_in[0];
    const float* gno  = (const float*)d_in[1];
    const float* bno  = (const float*)d_in[2];
    const float* Wq   = (const float*)d_in[3];
    const float* bq   = (const float*)d_in[4];
    const float* Wkv  = (const float*)d_in[5];
    const float* bkv  = (const float*)d_in[6];
    const float* Wout = (const float*)d_in[7];
    const float* bout = (const float*)d_in[8];
    const int*   topt = (const int*)d_in[9];
    float* out = (float*)d_out;

    char* ws = (char*)d_ws;
    // Region A (64 MB): feat(16) + q(16) + kv(32). Dead after repack_kernel;
    // reused as simBuf (4 heads x 16 MB) for the sim/topk sweep.
    float* feat = (float*)(ws + 0);
    float* q    = (float*)(ws + (size_t)TT * D * 4);
    float* kv   = (float*)(ws + (size_t)2 * TT * D * 4);
    size_t off  = (size_t)4 * TT * D * 4;                                    // 64 MB
    float* qh      = (float*)(ws + off); off += (size_t)NHB * NN * DH * 4;   // 17.8 MB
    float* kh      = (float*)(ws + off); off += (size_t)NHB * NN * DH * 4;
    float* vh      = (float*)(ws + off); off += (size_t)NHB * NN * DH * 4;
    int*   keptIdx = (int*)  (ws + off); off += (size_t)NHB * NN * CAP * 4;
    float* keptVal = (float*)(ws + off); off += (size_t)NHB * NN * CAP * 4;
    int*   keptCnt = (int*)  (ws + off); off += (size_t)NHB * NN * 4;
    float* colZ    = (float*)(ws + off); off += (size_t)NHB * NN * 4;
    int*   nE      = (int*)  (ws + off); off += 256;
    float* vsumE   = (float*)(ws + off); off += (size_t)NHB * DH * 4 + 192;  // pad to 256
    float* vsumAll = (float*)(ws + off); off += (size_t)NHB * DH * 4 + 192;
    float* outcat  = (float*)(ws + off); off += (size_t)TT * D * 4;          // 16 MB

    // simBuf: prefer tail of ws if it holds >4 heads, else alias region A (4 heads).
    size_t simBytesPerHead = (size_t)NN * NN * 4;                            // 16 MB
    size_t tail = (ws_size > off) ? (ws_size - off) : 0;
    int Gtail = (int)(tail / simBytesPerHead);
    float* simBuf;
    int G;
    if (Gtail > 4) {
        simBuf = (float*)(ws + off);
        G = (Gtail < NHB) ? Gtail : NHB;
    } else {
        simBuf = (float*)ws;   // region A, free after repack
        G = 4;
    }

    ln_kernel<<<TT, 256, 0, stream>>>(sink, gno, bno, feat);
    sgemm_bias<<<dim3(D / 64, TT / 64), 256, 0, stream>>>(feat, D, Wq, D, bq, q, D);
    sgemm_bias<<<dim3(2 * D / 64, TT / 64), 256, 0, stream>>>(feat, D, Wkv, 2 * D, bkv, kv, 2 * D);
    repack_kernel<<<((unsigned)NHB * NN * DH + 255) / 256, 256, 0, stream>>>(q, kv, sink, qh, kh, vh);
    hipMemsetAsync(colZ, 0, (size_t)NHB * NN * 4, stream);

    for (int hb0 = 0; hb0 < NHB; hb0 += G) {
        int gc = (NHB - hb0 < G) ? (NHB - hb0) : G;
        sim_kernel<<<dim3(NN / 64, NN / 64, gc), 256, 0, stream>>>(qh, kh, simBuf, hb0);
        topk_kernel<<<gc * 512, 256, 0, stream>>>(simBuf, hb0, topt, keptIdx, keptVal, keptCnt);
    }

    colz_kernel<<<((unsigned)NHB * NN * CAP + 255) / 256, 256, 0, stream>>>(keptIdx, keptVal, keptCnt, colZ);
    stats_kernel<<<NHB, 4 * DH, 0, stream>>>(colZ, vh, nE, vsumE, vsumAll);
    pv_kernel<<<NHB * NN, 128, 0, stream>>>(keptIdx, keptVal, keptCnt, colZ, vh, nE, vsumE, vsumAll, outcat, out);
    sgemm_bias<<<dim3(D / 64, TT / 64), 256, 0, stream>>>(outcat, D, Wout, D, bout, out, D + PED);
}